// Round 1
// baseline (2608.180 us; speedup 1.0000x reference)
//
#include <hip/hip_runtime.h>
#include <hip/hip_fp16.h>
#include <math.h>

// Problem dims
#define Hh 1024
#define Dd 512
#define Aa 1024
#define Vv 50257
#define Ss 128
#define NSTEP 25

// logits kernel tiling
#define ROWS_PER_BLK 16
#define NBLK_LOG ((Vv + ROWS_PER_BLK - 1) / ROWS_PER_BLK)   // 3142

// Workspace layout (float offsets)
#define OFF_H0     0        // 1024  hidden ping
#define OFF_H1     1024     // 1024  hidden pong
#define OFF_MERGE  2048     // 2048  [h_new, attn]
#define OFF_PM     4096     // 3142  per-block max
#define OFF_PL     8192     // 3142  per-block sumexp
#define OFF_PI     12288    // 3142  per-block argmax (int)
#define OFF_LSE    16384    // 25    per-step logsumexp
#define OFF_M      32768    // 131072  M = emb @ Wq  (128 x 1024)

// fp16 Wout copy at byte offset 1 MB (float offset 262144 > 163840 = end of OFF_M)
#define WOUTH_BYTE_OFF (1u << 20)
#define NG_CONV (50257u * 256u)   // groups of 8 floats

__device__ __forceinline__ float dot4(float4 a, float4 b) {
    return a.x * b.x + a.y * b.y + a.z * b.z + a.w * b.w;
}

// ---------------- Wout fp32 -> fp16 conversion (once per call) ----------------
__global__ void k_conv(const float4* __restrict__ src, uint4* __restrict__ dst, unsigned n8) {
    unsigned stride = gridDim.x * blockDim.x;
    for (unsigned g = blockIdx.x * blockDim.x + threadIdx.x; g < n8; g += stride) {
        float4 a = src[(size_t)g * 2], b = src[(size_t)g * 2 + 1];
        union { __half2 h[4]; uint4 u; } pk;
        pk.h[0] = __float22half2_rn(make_float2(a.x, a.y));
        pk.h[1] = __float22half2_rn(make_float2(a.z, a.w));
        pk.h[2] = __float22half2_rn(make_float2(b.x, b.y));
        pk.h[3] = __float22half2_rn(make_float2(b.z, b.w));
        dst[g] = pk.u;
    }
}

// ---------------- fold: M[s,h] = sum_a emb[s,a] * Wq[a,h]  (once per call) ----
__global__ void k_fold(const float* __restrict__ emb, const float* __restrict__ Wq,
                       float* __restrict__ ws) {
    __shared__ float se[Aa];
    int s = blockIdx.x;
    for (int a = threadIdx.x; a < Aa; a += 256) se[a] = emb[(size_t)s * Aa + a];
    __syncthreads();
    int h = threadIdx.x;
    float a0 = 0.f, a1 = 0.f, a2 = 0.f, a3 = 0.f;
    for (int a = 0; a < Aa; a++) {
        float e = se[a];
        const float* wr = Wq + (size_t)a * Hh;
        a0 += e * wr[h];
        a1 += e * wr[h + 256];
        a2 += e * wr[h + 512];
        a3 += e * wr[h + 768];
    }
    float* Mrow = ws + OFF_M + (size_t)s * Hh;
    Mrow[h] = a0; Mrow[h + 256] = a1; Mrow[h + 512] = a2; Mrow[h + 768] = a3;
}

// ---------------- init: h = hidden[-1] ----------------
__global__ void k_init(const float* __restrict__ hidden, float* __restrict__ ws) {
    int i = blockIdx.x * blockDim.x + threadIdx.x;
    if (i < Hh) ws[OFF_H0 + i] = hidden[i];
}

// ---------------- head: [prev-step argmax/LSE reduce] + GRU gates + cell -----
// grid 256 x 256. Every block redundantly reduces the NBLK_LOG partials so each
// block knows `word` locally (no extra kernel / sync). h is ping-pong buffered.
__global__ void k_head(int first, int par, int tprev,
                       const float* __restrict__ E, const float* __restrict__ W_ih,
                       const float* __restrict__ W_hh, const float* __restrict__ b_ih,
                       const float* __restrict__ b_hh, float* __restrict__ ws,
                       float* __restrict__ out_tok) {
    __shared__ float sm_[256], sl_[256];
    __shared__ int si_[256];
    __shared__ int s_word;
    int t = threadIdx.x;
    int word;
    if (first) {
        word = 1;   // SOS
    } else {
        const float* pm = ws + OFF_PM;
        const float* pl = ws + OFF_PL;
        const int* pi = (const int*)ws + OFF_PI;
        float m = -1e30f, l = 0.f; int idx = 0x7fffffff;
        for (int i = t; i < NBLK_LOG; i += 256) {
            float m2 = pm[i], l2 = pl[i]; int i2 = pi[i];
            float M = fmaxf(m, m2);
            float L = l * expf(m - M) + l2 * expf(m2 - M);
            idx = (m2 > m) ? i2 : ((m2 < m) ? idx : min(idx, i2));
            m = M; l = L;
        }
        sm_[t] = m; sl_[t] = l; si_[t] = idx;
        __syncthreads();
        for (int s = 128; s; s >>= 1) {
            if (t < s) {
                float m1 = sm_[t], l1 = sl_[t]; int i1 = si_[t];
                float m2 = sm_[t + s], l2 = sl_[t + s]; int i2 = si_[t + s];
                float M = fmaxf(m1, m2);
                sl_[t] = l1 * expf(m1 - M) + l2 * expf(m2 - M);
                si_[t] = (m2 > m1) ? i2 : ((m2 < m1) ? i1 : min(i1, i2));
                sm_[t] = M;
            }
            __syncthreads();
        }
        if (t == 0) {
            s_word = si_[0];
            if (blockIdx.x == 0) {
                out_tok[tprev] = (float)si_[0];
                ws[OFF_LSE + tprev] = sm_[0] + logf(sl_[0]);
            }
        }
        __syncthreads();
        word = s_word;
    }

    // ---- GRU gates + cell update: wave per row, 6 dot products ----
    int lane = t & 63;
    int row = blockIdx.x * 4 + (t >> 6);          // 0..1023
    const float* hprev = ws + (par ? OFF_H1 : OFF_H0);
    float* hnext = ws + (par ? OFF_H0 : OFF_H1);
    const float4* x4 = (const float4*)(E + (size_t)word * Dd);
    const float4* h4 = (const float4*)hprev;
    const float4* wir = (const float4*)(W_ih + (size_t)row * Dd);
    const float4* wiz = (const float4*)(W_ih + (size_t)(Hh + row) * Dd);
    const float4* win = (const float4*)(W_ih + (size_t)(2 * Hh + row) * Dd);
    const float4* whr = (const float4*)(W_hh + (size_t)row * Hh);
    const float4* whz = (const float4*)(W_hh + (size_t)(Hh + row) * Hh);
    const float4* whn = (const float4*)(W_hh + (size_t)(2 * Hh + row) * Hh);
    float aIr = 0.f, aIz = 0.f, aIn = 0.f, aHr = 0.f, aHz = 0.f, aHn = 0.f;
    #pragma unroll
    for (int it = 0; it < 2; it++) {
        int k = it * 64 + lane;
        float4 b = x4[k];
        aIr += dot4(wir[k], b); aIz += dot4(wiz[k], b); aIn += dot4(win[k], b);
    }
    #pragma unroll
    for (int it = 0; it < 4; it++) {
        int k = it * 64 + lane;
        float4 b = h4[k];
        aHr += dot4(whr[k], b); aHz += dot4(whz[k], b); aHn += dot4(whn[k], b);
    }
    for (int off = 32; off; off >>= 1) {
        aIr += __shfl_down(aIr, off); aIz += __shfl_down(aIz, off); aIn += __shfl_down(aIn, off);
        aHr += __shfl_down(aHr, off); aHz += __shfl_down(aHz, off); aHn += __shfl_down(aHn, off);
    }
    if (lane == 0) {
        float ir = aIr + b_ih[row], iz = aIz + b_ih[Hh + row], inn = aIn + b_ih[2 * Hh + row];
        float hr = aHr + b_hh[row], hz = aHz + b_hh[Hh + row], hn = aHn + b_hh[2 * Hh + row];
        float r = 1.f / (1.f + expf(-(ir + hr)));
        float z = 1.f / (1.f + expf(-(iz + hz)));
        float n = tanhf(inn + r * hn);
        float hv = (1.f - z) * n + z * hprev[row];
        hnext[row] = hv;
        ws[OFF_MERGE + row] = hv;
    }
}

// ---------------- attn: scores (via folded M) + softmax + combine ------------
// grid 8 x 256. Scores+softmax computed redundantly per block (tiny) to avoid
// any cross-block sync; each block produces 128 of the 1024 attn outputs.
__global__ void k_attn(const float* __restrict__ emb, float* __restrict__ ws,
                       float* __restrict__ outw) {
    __shared__ float sh[Hh];
    __shared__ float sc[Ss];
    __shared__ float red[256];
    int t = threadIdx.x;
    for (int i = t; i < Hh; i += 256) sh[i] = ws[OFF_MERGE + i];
    __syncthreads();
    // scores: 2 threads per s, each over half of H
    {
        int s = t & 127, half = t >> 7;
        const float4* M4 = (const float4*)(ws + OFF_M + (size_t)s * Hh + half * 512);
        const float4* h44 = (const float4*)(sh + half * 512);
        float a0 = 0.f, a1 = 0.f, a2 = 0.f, a3 = 0.f;
        #pragma unroll
        for (int k = 0; k < 128; k += 4) {
            a0 += dot4(M4[k], h44[k]);
            a1 += dot4(M4[k + 1], h44[k + 1]);
            a2 += dot4(M4[k + 2], h44[k + 2]);
            a3 += dot4(M4[k + 3], h44[k + 3]);
        }
        red[t] = (a0 + a1) + (a2 + a3);
    }
    __syncthreads();
    if (t < 128) sc[t] = red[t] + red[t + 128];
    __syncthreads();
    // softmax over sc[0..127]
    float v = (t < 128) ? sc[t] : -1e30f;
    float m = v;
    for (int off = 32; off; off >>= 1) m = fmaxf(m, __shfl_down(m, off));
    if ((t & 63) == 0) red[t >> 6] = m;
    __syncthreads();
    float mm = fmaxf(fmaxf(red[0], red[1]), fmaxf(red[2], red[3]));
    __syncthreads();
    float e = (t < 128) ? expf(v - mm) : 0.f;
    float sum = e;
    for (int off = 32; off; off >>= 1) sum += __shfl_down(sum, off);
    if ((t & 63) == 0) red[t >> 6] = sum;
    __syncthreads();
    float ssum = red[0] + red[1] + red[2] + red[3];
    if (t < 128) {
        float w = e / ssum;
        sc[t] = w;
        if (blockIdx.x == 0) outw[t] = w;
    }
    __syncthreads();
    // combine: this block covers a in [blockIdx*128, +128); 2 threads per a
    {
        int a = blockIdx.x * 128 + (t & 127);
        int half = t >> 7;
        const float* eb = emb + (size_t)(half * 64) * Aa + a;
        const float* scp = sc + half * 64;
        float a0 = 0.f, a1 = 0.f;
        #pragma unroll
        for (int s = 0; s < 64; s += 2) {
            a0 += scp[s] * eb[(size_t)s * Aa];
            a1 += scp[s + 1] * eb[(size_t)(s + 1) * Aa];
        }
        red[t] = a0 + a1;
    }
    __syncthreads();
    if (t < 128) {
        int a = blockIdx.x * 128 + t;
        ws[OFF_MERGE + Hh + a] = red[t] + red[t + 128];
    }
}

// ---------------- logits: fp16 matvec, 16 rows/block, fused partial reduce ---
__global__ void k_logits(const uint4* __restrict__ WoutH, const float* __restrict__ bout,
                         float* __restrict__ ws, float* __restrict__ lp_out) {
    __shared__ float4 smg[512];     // merge: 2048 floats
    __shared__ float wm[4], wl[4];
    __shared__ int wi_[4];
    const float4* mg = (const float4*)(ws + OFF_MERGE);
    for (int i = threadIdx.x; i < 512; i += 256) smg[i] = mg[i];
    __syncthreads();
    int wave = threadIdx.x >> 6, lane = threadIdx.x & 63;
    int row0 = blockIdx.x * ROWS_PER_BLK + wave * 4;
    const uint4* w0 = WoutH + (size_t)min(row0 + 0, Vv - 1) * 256;
    const uint4* w1 = WoutH + (size_t)min(row0 + 1, Vv - 1) * 256;
    const uint4* w2 = WoutH + (size_t)min(row0 + 2, Vv - 1) * 256;
    const uint4* w3 = WoutH + (size_t)min(row0 + 3, Vv - 1) * 256;
    float acc0 = 0.f, acc1 = 0.f, acc2 = 0.f, acc3 = 0.f;
    #pragma unroll
    for (int it = 0; it < 4; it++) {
        int k = it * 64 + lane;
        float4 m0 = smg[2 * k], m1 = smg[2 * k + 1];
        {
            union { uint4 u; __half2 h[4]; } pk; pk.u = w0[k];
            float2 f0 = __half22float2(pk.h[0]), f1 = __half22float2(pk.h[1]);
            float2 f2 = __half22float2(pk.h[2]), f3 = __half22float2(pk.h[3]);
            acc0 += f0.x * m0.x + f0.y * m0.y + f1.x * m0.z + f1.y * m0.w
                  + f2.x * m1.x + f2.y * m1.y + f3.x * m1.z + f3.y * m1.w;
        }
        {
            union { uint4 u; __half2 h[4]; } pk; pk.u = w1[k];
            float2 f0 = __half22float2(pk.h[0]), f1 = __half22float2(pk.h[1]);
            float2 f2 = __half22float2(pk.h[2]), f3 = __half22float2(pk.h[3]);
            acc1 += f0.x * m0.x + f0.y * m0.y + f1.x * m0.z + f1.y * m0.w
                  + f2.x * m1.x + f2.y * m1.y + f3.x * m1.z + f3.y * m1.w;
        }
        {
            union { uint4 u; __half2 h[4]; } pk; pk.u = w2[k];
            float2 f0 = __half22float2(pk.h[0]), f1 = __half22float2(pk.h[1]);
            float2 f2 = __half22float2(pk.h[2]), f3 = __half22float2(pk.h[3]);
            acc2 += f0.x * m0.x + f0.y * m0.y + f1.x * m0.z + f1.y * m0.w
                  + f2.x * m1.x + f2.y * m1.y + f3.x * m1.z + f3.y * m1.w;
        }
        {
            union { uint4 u; __half2 h[4]; } pk; pk.u = w3[k];
            float2 f0 = __half22float2(pk.h[0]), f1 = __half22float2(pk.h[1]);
            float2 f2 = __half22float2(pk.h[2]), f3 = __half22float2(pk.h[3]);
            acc3 += f0.x * m0.x + f0.y * m0.y + f1.x * m0.z + f1.y * m0.w
                  + f2.x * m1.x + f2.y * m1.y + f3.x * m1.z + f3.y * m1.w;
        }
    }
    for (int off = 32; off; off >>= 1) {
        acc0 += __shfl_down(acc0, off); acc1 += __shfl_down(acc1, off);
        acc2 += __shfl_down(acc2, off); acc3 += __shfl_down(acc3, off);
    }
    if (lane == 0) {
        float m = -1e30f, l = 0.f; int idx = 0x7fffffff;
        float accs[4] = {acc0, acc1, acc2, acc3};
        #pragma unroll
        for (int r = 0; r < 4; r++) {
            int row = row0 + r;
            if (row < Vv) {
                float v = accs[r] + bout[row];
                lp_out[row] = v;                       // raw logit; LSE fixup later
                if (v > m) { l = l * expf(m - v) + 1.f; m = v; idx = row; }
                else       { l += expf(v - m); }
            }
        }
        wm[wave] = m; wl[wave] = l; wi_[wave] = idx;
    }
    __syncthreads();
    if (threadIdx.x == 0) {
        float m = wm[0], l = wl[0]; int idx = wi_[0];
        #pragma unroll
        for (int wv = 1; wv < 4; wv++) {
            float m2 = wm[wv], l2 = wl[wv]; int i2 = wi_[wv];
            float M = fmaxf(m, m2);
            l = l * expf(m - M) + l2 * expf(m2 - M);
            idx = (m2 > m) ? i2 : ((m2 < m) ? idx : min(idx, i2));
            m = M;
        }
        ws[OFF_PM + blockIdx.x] = m;
        ws[OFF_PL + blockIdx.x] = l;
        ((int*)ws)[OFF_PI + blockIdx.x] = idx;
    }
}

// ---------------- tail: reduce partials of the last step ----------------
__global__ void k_tail(float* __restrict__ ws, float* __restrict__ out_tok) {
    __shared__ float sm_[256], sl_[256];
    __shared__ int si_[256];
    int t = threadIdx.x;
    const float* pm = ws + OFF_PM;
    const float* pl = ws + OFF_PL;
    const int* pi = (const int*)ws + OFF_PI;
    float m = -1e30f, l = 0.f; int idx = 0x7fffffff;
    for (int i = t; i < NBLK_LOG; i += 256) {
        float m2 = pm[i], l2 = pl[i]; int i2 = pi[i];
        float M = fmaxf(m, m2);
        float L = l * expf(m - M) + l2 * expf(m2 - M);
        idx = (m2 > m) ? i2 : ((m2 < m) ? idx : min(idx, i2));
        m = M; l = L;
    }
    sm_[t] = m; sl_[t] = l; si_[t] = idx;
    __syncthreads();
    for (int s = 128; s; s >>= 1) {
        if (t < s) {
            float m1 = sm_[t], l1 = sl_[t]; int i1 = si_[t];
            float m2 = sm_[t + s], l2 = sl_[t + s]; int i2 = si_[t + s];
            float M = fmaxf(m1, m2);
            sl_[t] = l1 * expf(m1 - M) + l2 * expf(m2 - M);
            si_[t] = (m2 > m1) ? i2 : ((m2 < m1) ? i1 : min(i1, i2));
            sm_[t] = M;
        }
        __syncthreads();
    }
    if (t == 0) {
        out_tok[NSTEP - 1] = (float)si_[0];
        ws[OFF_LSE + NSTEP - 1] = sm_[0] + logf(sl_[0]);
    }
}

// ---------------- fixup: lp[t][i] = logit - lse[t], all steps batched --------
__global__ void k_fixup(const float* __restrict__ ws, float* __restrict__ out_lp) {
    int ts = blockIdx.y;
    int i = blockIdx.x * 256 + threadIdx.x;
    if (i < Vv) out_lp[(size_t)ts * Vv + i] -= ws[OFF_LSE + ts];
}

extern "C" void kernel_launch(void* const* d_in, const int* in_sizes, int n_in,
                              void* d_out, int out_size, void* d_ws, size_t ws_size,
                              hipStream_t stream) {
    const float* hidden = (const float*)d_in[0];
    const float* emb    = (const float*)d_in[1];
    const float* E      = (const float*)d_in[2];
    const float* W_ih   = (const float*)d_in[3];
    const float* W_hh   = (const float*)d_in[4];
    const float* b_ih   = (const float*)d_in[5];
    const float* b_hh   = (const float*)d_in[6];
    const float* Wq     = (const float*)d_in[7];
    const float* Wout   = (const float*)d_in[8];
    const float* bout   = (const float*)d_in[9];

    float* ws = (float*)d_ws;
    uint4* WoutH = (uint4*)((char*)d_ws + WOUTH_BYTE_OFF);
    float* out_lp  = (float*)d_out;                      // 25 x 50257
    float* out_w   = out_lp + (size_t)NSTEP * Vv;        // 25 x 128
    float* out_tok = out_w + (size_t)NSTEP * Ss;         // 25

    k_conv<<<8192, 256, 0, stream>>>((const float4*)Wout, WoutH, NG_CONV);
    k_fold<<<Ss, 256, 0, stream>>>(emb, Wq, ws);
    k_init<<<4, 256, 0, stream>>>(hidden, ws);
    for (int t = 0; t < NSTEP; t++) {
        k_head  <<<256, 256, 0, stream>>>(t == 0 ? 1 : 0, t & 1, t - 1,
                                          E, W_ih, W_hh, b_ih, b_hh, ws, out_tok);
        k_attn  <<<8, 256, 0, stream>>>(emb, ws, out_w + (size_t)t * Ss);
        k_logits<<<NBLK_LOG, 256, 0, stream>>>((const uint4*)WoutH, bout, ws,
                                               out_lp + (size_t)t * Vv);
    }
    k_tail <<<1, 256, 0, stream>>>(ws, out_tok);
    k_fixup<<<dim3((Vv + 255) / 256, NSTEP), 256, 0, stream>>>(ws, out_lp);
}